// Round 5
// baseline (345.610 us; speedup 1.0000x reference)
//
#include <hip/hip_runtime.h>

#define N_  4096   // H*W
#define M_  1024   // pooled

typedef short bf16x8 __attribute__((ext_vector_type(8)));
typedef float f32x4  __attribute__((ext_vector_type(4)));

#define MFMA16(A,B,C) __builtin_amdgcn_mfma_f32_16x16x32_bf16(A,B,C,0,0,0)

__device__ __forceinline__ unsigned short f2b(float f){
    union { float f; unsigned u; } v; v.f = f;
    unsigned r = v.u + 0x7FFFu + ((v.u >> 16) & 1u);
    return (unsigned short)(r >> 16);
}
__device__ __forceinline__ unsigned packbf(float lo, float hi){
    return (unsigned)f2b(lo) | ((unsigned)f2b(hi) << 16);
}

// ---------------- k0: convert stacked weights wf|wg|wh -> bf16 ----------------
__global__ __launch_bounds__(256)
void k0_wcvt(const float* __restrict__ wf, const float* __restrict__ wg,
             const float* __restrict__ wh, short* __restrict__ wsB) {
    const int i4 = (blockIdx.x * 256 + threadIdx.x) * 4;    // 48 blocks -> 49152 elems
    const float* src = (i4 < 8192) ? (wf + i4) : (i4 < 16384) ? (wg + (i4 - 8192))
                                               : (wh + (i4 - 16384));
    float4 v = *(const float4*)src;
    uint2 o; o.x = packbf(v.x, v.y); o.y = packbf(v.z, v.w);
    *(uint2*)(wsB + i4) = o;
}

// ---------------- k1: MFMA projections + maxpool; emits fT, gT, hM (bf16) ------
// fT[b][n][32]  gT[b][m][32]  hM[b][c=128][m=1024]
// K=256 split into two 128-halves, double-buffered in LDS (32KB each).
__global__ __launch_bounds__(512, 4)
void k1_proj(const float* __restrict__ x, const short* __restrict__ wsB,
             const float* __restrict__ wo,
             short* __restrict__ fT, short* __restrict__ gT,
             short* __restrict__ hM, short* __restrict__ woB) {
    __shared__ __align__(64) char sm[65536];
    const int t    = threadIdx.x;
    const int b    = blockIdx.x >> 5;
    const int rp   = blockIdx.x & 31;
    const int nb   = rp * 128;
    const int mb   = rp * 32;
    const int lane = t & 63;
    const int w    = t >> 6;            // wave 0..7
    const int lr   = lane & 15, lg = lane >> 4;

    // staging map: thread handles c-pair (2*p5, 2*p5+1) x 16 n
    const int p5  = t & 63;
    const int n0s = (t >> 6) * 16;
    const float* xb = x + ((size_t)(b * 256)) * N_ + nb + n0s;

    // ---- prologue: load half0 (c 0..127) ----
    float4 r0[4], r1[4];
#pragma unroll
    for (int q = 0; q < 4; ++q) {
        r0[q] = *(const float4*)(xb + (size_t)(2 * p5)     * N_ + q * 4);
        r1[q] = *(const float4*)(xb + (size_t)(2 * p5 + 1) * N_ + q * 4);
    }
    // wo -> bf16 (first 64 blocks, independent work)
    if (blockIdx.x < 64) {
        const int i = blockIdx.x * 512 + t;
        woB[i] = (short)f2b(wo[i]);
    }
    // pack+write half0: buf0 at [0,32768): addr = (n*256 + cl*2) ^ ((n&7)<<4)
#pragma unroll
    for (int q = 0; q < 4; ++q) {
        const float a0[4] = {r0[q].x, r0[q].y, r0[q].z, r0[q].w};
        const float a1[4] = {r1[q].x, r1[q].y, r1[q].z, r1[q].w};
#pragma unroll
        for (int e = 0; e < 4; ++e) {
            const int n = n0s + q * 4 + e;
            *(unsigned*)(sm + ((n * 256 + 4 * p5) ^ ((n & 7) << 4))) = packbf(a0[e], a1[e]);
        }
    }
    __syncthreads();

    // ---- issue half1 loads (c 128..255) ----
#pragma unroll
    for (int q = 0; q < 4; ++q) {
        r0[q] = *(const float4*)(xb + (size_t)(128 + 2 * p5) * N_ + q * 4);
        r1[q] = *(const float4*)(xb + (size_t)(129 + 2 * p5) * N_ + q * 4);
    }

    // ---- compute half0 ----
    f32x4 acc[12];
#pragma unroll
    for (int ot = 0; ot < 12; ++ot) acc[ot] = (f32x4){0.f, 0.f, 0.f, 0.f};
    {
        const int n = w * 16 + lr;
        bf16x8 xA[4];
#pragma unroll
        for (int kc = 0; kc < 4; ++kc)
            xA[kc] = *(const bf16x8*)(sm + ((n * 256 + (kc * 32 + lg * 8) * 2) ^ ((n & 7) << 4)));
#pragma unroll
        for (int ot = 0; ot < 12; ++ot) {
            const short* wrow = wsB + (size_t)(ot * 16 + lr) * 256 + lg * 8;
#pragma unroll
            for (int kc = 0; kc < 4; ++kc) {
                bf16x8 wB = *(const bf16x8*)(wrow + kc * 32);
                acc[ot] = MFMA16(xA[kc], wB, acc[ot]);
            }
        }
    }
    // pack+write half1 into buf1 at [32768,65536)
#pragma unroll
    for (int q = 0; q < 4; ++q) {
        const float a0[4] = {r0[q].x, r0[q].y, r0[q].z, r0[q].w};
        const float a1[4] = {r1[q].x, r1[q].y, r1[q].z, r1[q].w};
#pragma unroll
        for (int e = 0; e < 4; ++e) {
            const int n = n0s + q * 4 + e;
            *(unsigned*)(sm + 32768 + ((n * 256 + 4 * p5) ^ ((n & 7) << 4))) = packbf(a0[e], a1[e]);
        }
    }
    __syncthreads();
    // ---- compute half1 ----
    {
        const int n = w * 16 + lr;
        bf16x8 xA[4];
#pragma unroll
        for (int kc = 0; kc < 4; ++kc)
            xA[kc] = *(const bf16x8*)(sm + 32768 + ((n * 256 + (kc * 32 + lg * 8) * 2) ^ ((n & 7) << 4)));
#pragma unroll
        for (int ot = 0; ot < 12; ++ot) {
            const short* wrow = wsB + (size_t)(ot * 16 + lr) * 256 + 128 + lg * 8;
#pragma unroll
            for (int kc = 0; kc < 4; ++kc) {
                bf16x8 wB = *(const bf16x8*)(wrow + kc * 32);
                acc[ot] = MFMA16(xA[kc], wB, acc[ot]);
            }
        }
    }
    __syncthreads();   // xs dead; reuse LDS as raw[o=192][n=128] (swizzled)

#pragma unroll
    for (int ot = 0; ot < 12; ++ot) {
        const int o = ot * 16 + lr;
        const int n = w * 16 + lg * 4;
        const int base = o * 256 + n * 2;
        *(unsigned*)(sm + ((base)     ^ ((o & 7) << 4))) = packbf(acc[ot][0], acc[ot][1]);
        *(unsigned*)(sm + ((base + 4) ^ ((o & 7) << 4))) = packbf(acc[ot][2], acc[ot][3]);
    }
    __syncthreads();

    // ---- f store: fT[n][0..31] ----
    {
        const int n = t & 127, oq = t >> 7;     // oq 0..3
        unsigned pk[4];
#pragma unroll
        for (int v = 0; v < 4; ++v) {
            const int o0 = oq * 8 + v * 2;
            unsigned short b0 = *(unsigned short*)(sm + (((o0)     * 256 + n * 2) ^ (((o0)     & 7) << 4)));
            unsigned short b1 = *(unsigned short*)(sm + (((o0 + 1) * 256 + n * 2) ^ (((o0 + 1) & 7) << 4)));
            pk[v] = (unsigned)b0 | ((unsigned)b1 << 16);
        }
        *(uint4*)(fT + ((size_t)(b * N_ + nb + n)) * 32 + oq * 8) = make_uint4(pk[0], pk[1], pk[2], pk[3]);
    }

    // ---- 2x2 maxpool of rows 32..191 -> g (to pg LDS), h (to hM global) ----
    {
        const int j  = t & 31;          // pooled col
        const int ob = t >> 5;          // 0..15
#pragma unroll
        for (int i = 0; i < 10; ++i) {
            const int oo = ob + i * 16;             // 0..159
            const int ro = 32 + oo;
            const int base = ro * 256;
            const unsigned u0 = *(unsigned*)(sm + ((base + 4 * j)       ^ ((ro & 7) << 4)));
            const unsigned u1 = *(unsigned*)(sm + ((base + 128 + 4 * j) ^ ((ro & 7) << 4)));
            union { unsigned u; float f; } c0, c1, c2, c3;
            c0.u = u0 << 16; c1.u = u0 & 0xFFFF0000u;
            c2.u = u1 << 16; c3.u = u1 & 0xFFFF0000u;
            const float mx = fmaxf(fmaxf(c0.f, c1.f), fmaxf(c2.f, c3.f));
            if (oo < 32) {
                *(unsigned short*)(sm + 49664 + j * 68 + oo * 2) = f2b(mx);
            } else {
                hM[((size_t)(b * 128 + (oo - 32))) * M_ + mb + j] = (short)f2b(mx);
            }
        }
    }
    __syncthreads();
    // ---- g store from pg: gT[m][0..31] ----
    if (t < 128) {
        const int jm = t >> 2, q = t & 3;
        const char* pgb = sm + 49664 + jm * 68 + q * 16;
        unsigned v0 = *(unsigned*)(pgb + 0), v1 = *(unsigned*)(pgb + 4),
                 v2 = *(unsigned*)(pgb + 8), v3 = *(unsigned*)(pgb + 12);
        *(uint4*)(gT + ((size_t)(b * M_ + mb + jm)) * 32 + q * 8) = make_uint4(v0, v1, v2, v3);
    }
}

// ---------------- k2: flash attention (swapped QK^T) + wo epilogue ------------
// Register-prefetch of gA (S-tile A-operand) and hM chunk one K-tile ahead.
__global__ __launch_bounds__(256, 3)
void k2_attn(const short* __restrict__ fT, const short* __restrict__ gT,
             const short* __restrict__ hM, const short* __restrict__ woB,
             const float* __restrict__ x, const float* __restrict__ gam,
             float* __restrict__ out) {
    __shared__ __align__(64) char sm[49152];   // [0,32768) hs | [32768,49152) P_lds ; OT unions [0,16384)
    const int t    = threadIdx.x;
    const int lane = t & 63;
    const int w    = t >> 6;            // wave 0..3, owns n-sub w*16
    const int lr   = lane & 15, lg = lane >> 4;
    const int b    = blockIdx.x >> 6;
    const int nt   = blockIdx.x & 63;
    const int n0   = nt * 64;

    const f32x4 z4 = (f32x4){0.f, 0.f, 0.f, 0.f};

    // hoisted f B-fragment (this wave's 16 n-columns, full K=32)
    const bf16x8 fB = *(const bf16x8*)(fT + ((size_t)(b * N_ + n0 + w * 16 + lr)) * 32 + lg * 8);

    f32x4 acc[8];
#pragma unroll
    for (int j = 0; j < 8; ++j) acc[j] = z4;
    float M = -1e30f, Lp = 0.f;

    const int pbase = 32768 + w * 4096;
    const int swz   = (lr & 7) << 4;

    // per-lane bases for prefetched operands
    const short* gA0   = gT + ((size_t)(b * M_) + lr) * 32 + lg * 8;     // + (m0+mt*16)*32
    const int    hslc  = (t >> 4);                                        // per-i: c = hslc + (i*256>>4)
    const int    hslp  = (t & 15);
    const short* hMb   = hM + (size_t)(b * 128) * M_;

    // prologue: prefetch tile 0
    bf16x8 gv[8], hv[8];
#pragma unroll
    for (int mt = 0; mt < 8; ++mt)
        gv[mt] = *(const bf16x8*)(gA0 + (size_t)(mt * 16) * 32);
#pragma unroll
    for (int i = 0; i < 8; ++i) {
        const int c = hslc + i * 16;
        hv[i] = *(const bf16x8*)(hMb + (size_t)c * M_ + hslp * 8);
    }

    for (int mt8 = 0; mt8 < 8; ++mt8) {
        const int m0 = mt8 * 128;
        __syncthreads();   // previous PV done reading hs
        // commit prefetched h chunk to LDS: hs[c=128][m=128] swizzled
#pragma unroll
        for (int i = 0; i < 8; ++i) {
            const int c = hslc + i * 16;
            *(bf16x8*)(sm + ((c * 256 + hslp * 16) ^ ((c & 7) << 4))) = hv[i];
        }
        // S^T[m][n] via MFMA from prefetched registers (no memory dependency)
        f32x4 s[8];
#pragma unroll
        for (int mt = 0; mt < 8; ++mt)
            s[mt] = MFMA16(gv[mt], fB, z4);
        // issue next tile's prefetch (overlaps softmax + PV)
        if (mt8 < 7) {
            const int m1 = m0 + 128;
#pragma unroll
            for (int mt = 0; mt < 8; ++mt)
                gv[mt] = *(const bf16x8*)(gA0 + (size_t)(m1 + mt * 16) * 32);
#pragma unroll
            for (int i = 0; i < 8; ++i) {
                const int c = hslc + i * 16;
                hv[i] = *(const bf16x8*)(hMb + (size_t)c * M_ + m1 + hslp * 8);
            }
        }
        // online softmax over m (in-lane 32 + cross-group shfl)
        float pm = -1e30f;
#pragma unroll
        for (int mt = 0; mt < 8; ++mt)
            pm = fmaxf(pm, fmaxf(fmaxf(s[mt][0], s[mt][1]), fmaxf(s[mt][2], s[mt][3])));
        pm = fmaxf(pm, __shfl_xor(pm, 16));
        pm = fmaxf(pm, __shfl_xor(pm, 32));
        const float Mn = fmaxf(M, pm);
        const float scale = __expf(M - Mn);
        M = Mn;
        float ps = 0.f;
#pragma unroll
        for (int mt = 0; mt < 8; ++mt) {
#pragma unroll
            for (int r = 0; r < 4; ++r) {
                const float p = __expf(s[mt][r] - Mn);
                s[mt][r] = p; ps += p;
            }
        }
        Lp = Lp * scale + ps;
        // P -> own-wave LDS region [n=16][m=128] bf16 swizzled
#pragma unroll
        for (int mt = 0; mt < 8; ++mt) {
            const int base = lr * 256 + (mt * 16 + lg * 4) * 2;
            *(unsigned*)(sm + pbase + ((base)     ^ swz)) = packbf(s[mt][0], s[mt][1]);
            *(unsigned*)(sm + pbase + ((base + 4) ^ swz)) = packbf(s[mt][2], s[mt][3]);
        }
        // rescale running accumulator (scale lives at lane lr == n)
        const float sc0 = __shfl(scale, lg * 4 + 0);
        const float sc1 = __shfl(scale, lg * 4 + 1);
        const float sc2 = __shfl(scale, lg * 4 + 2);
        const float sc3 = __shfl(scale, lg * 4 + 3);
#pragma unroll
        for (int cj = 0; cj < 8; ++cj) {
            acc[cj][0] *= sc0; acc[cj][1] *= sc1; acc[cj][2] *= sc2; acc[cj][3] *= sc3;
        }
        __syncthreads();   // hs visible to all waves
        // PV: acc[n][c] += P[n][m] * h[m][c]
#pragma unroll
        for (int kc = 0; kc < 4; ++kc) {
            const bf16x8 pA = *(const bf16x8*)(sm + pbase + ((lr * 256 + (kc * 32 + lg * 8) * 2) ^ swz));
#pragma unroll
            for (int cj = 0; cj < 8; ++cj) {
                const int c = cj * 16 + lr;
                const bf16x8 hB = *(const bf16x8*)(sm + ((c * 256 + (kc * 32 + lg * 8) * 2) ^ ((c & 7) << 4)));
                acc[cj] = MFMA16(pA, hB, acc[cj]);
            }
        }
    }
    // finalize 1/L
    Lp += __shfl_xor(Lp, 16);
    Lp += __shfl_xor(Lp, 32);
    const float inv = 1.f / Lp;
    const float iv0 = __shfl(inv, lg * 4 + 0), iv1 = __shfl(inv, lg * 4 + 1),
                iv2 = __shfl(inv, lg * 4 + 2), iv3 = __shfl(inv, lg * 4 + 3);
    __syncthreads();   // hs dead
    // OT[n=64][c=128] bf16 swizzled at base 0
#pragma unroll
    for (int cj = 0; cj < 8; ++cj) {
        const int c = cj * 16 + lr;
        const float vv[4] = {acc[cj][0] * iv0, acc[cj][1] * iv1, acc[cj][2] * iv2, acc[cj][3] * iv3};
#pragma unroll
        for (int r = 0; r < 4; ++r) {
            const int n = w * 16 + lg * 4 + r;
            *(unsigned short*)(sm + ((n * 256 + c * 2) ^ ((n & 7) << 4))) = f2b(vv[r]);
        }
    }
    __syncthreads();
    // epilogue: out[oc][n] = gamma * (wo . O^T) + x
    const float gamma = gam[0];
#pragma unroll
    for (int ti = 0; ti < 4; ++ti) {
        const int oc0 = w * 64 + ti * 16;
        bf16x8 wA[4];
#pragma unroll
        for (int kc = 0; kc < 4; ++kc)
            wA[kc] = *(const bf16x8*)(woB + (size_t)(oc0 + lr) * 128 + kc * 32 + lg * 8);
#pragma unroll
        for (int ni = 0; ni < 4; ++ni) {
            f32x4 e = z4;
#pragma unroll
            for (int kc = 0; kc < 4; ++kc) {
                const int n = ni * 16 + lr;
                const bf16x8 oB = *(const bf16x8*)(sm + ((n * 256 + (kc * 32 + lg * 8) * 2) ^ swz));
                e = MFMA16(wA[kc], oB, e);
            }
#pragma unroll
            for (int r = 0; r < 4; ++r) {
                const int oc = oc0 + lg * 4 + r;
                const size_t idx = ((size_t)(b * 256 + oc)) * N_ + n0 + ni * 16 + lr;
                out[idx] = gamma * e[r] + x[idx];
            }
        }
    }
}

extern "C" void kernel_launch(void* const* d_in, const int* in_sizes, int n_in,
                              void* d_out, int out_size, void* d_ws, size_t ws_size,
                              hipStream_t stream) {
    (void)in_sizes; (void)n_in; (void)out_size; (void)ws_size;
    const float* x   = (const float*)d_in[0];
    const float* wf  = (const float*)d_in[1];
    const float* wg  = (const float*)d_in[2];
    const float* wh  = (const float*)d_in[3];
    const float* wo  = (const float*)d_in[4];
    const float* gam = (const float*)d_in[5];
    float* out = (float*)d_out;

    short* ws  = (short*)d_ws;
    short* wsB = ws;                       // 49152
    short* woB = ws + 49152;               // 32768
    short* fT  = ws + 81920;               // 16*4096*32 = 2097152
    short* gT  = ws + 2179072;             // 16*1024*32 = 524288
    short* hM  = ws + 2703360;             // 16*128*1024 = 2097152

    k0_wcvt<<<dim3(48),   dim3(256), 0, stream>>>(wf, wg, wh, wsB);
    k1_proj<<<dim3(512),  dim3(512), 0, stream>>>(x, wsB, wo, fT, gT, hM, woB);
    k2_attn<<<dim3(1024), dim3(256), 0, stream>>>(fT, gT, hM, woB, x, gam, out);
}